// Round 4
// baseline (11588.079 us; speedup 1.0000x reference)
//
#include <hip/hip_runtime.h>

#define TT 1024
#define LOG2E 1.44269504088896340736f

typedef __attribute__((ext_vector_type(8))) short s16x8;
typedef __attribute__((ext_vector_type(4))) float f32x4;
typedef __attribute__((ext_vector_type(4))) unsigned int u32x4;
typedef __attribute__((ext_vector_type(2))) unsigned int u32x2;

__device__ __forceinline__ float ex2(float x){ return __builtin_amdgcn_exp2f(x); }
__device__ __forceinline__ float rcp_(float x){ return __builtin_amdgcn_rcpf(x); }
__device__ __forceinline__ float sigm(float x){ return rcp_(1.f + ex2(-LOG2E*x)); }
__device__ __forceinline__ float tanh_(float x){
  float t = ex2(2.f*LOG2E*x);
  return 1.f - 2.f*rcp_(t + 1.f);
}
__device__ __forceinline__ unsigned short f2bf(float f){
  unsigned int u = __float_as_uint(f);
  u += 0x7fffu + ((u>>16)&1u);
  return (unsigned short)(u>>16);
}
__device__ __forceinline__ float bflo(unsigned int u){ return __uint_as_float(u << 16); }
__device__ __forceinline__ float bfhi(unsigned int u){ return __uint_as_float(u & 0xffff0000u); }

// ---------------------------------------------------------------------------
// Phase 0: pack weights, B-fragment layout, bf16.
// Wpk gates: [d(2)][slice(8)][tau(8)][s(9)][lane(64)][8]
//   col = (tau>>1)*256 + slice*32 + 16*(tau&1) + (lane&15)   (gate g = tau>>1)
//   ko  = (lane>>4)*8 + j ; k-chunk s<8 -> Whh[col][s*32+ko];
//   s==8: ko<19 -> Wih[col][ko]; ko==19 -> bias[col]; else 0   (A has 1.0 at ko19)
// Wyk: [d][tauy(2)][s(8)][lane][8]: col = tauy*16+(lane&15); outW[col][d*256+s*32+ko]
// Also zeroes the 16 sync flags.
// ---------------------------------------------------------------------------
__global__ __launch_bounds__(256) void pack_weights(
    const float* __restrict__ WhhF, const float* __restrict__ WihF, const float* __restrict__ bF,
    const float* __restrict__ WhhB, const float* __restrict__ WihB, const float* __restrict__ bB,
    const float* __restrict__ outW,
    unsigned short* __restrict__ Wpk, unsigned short* __restrict__ Wyk, int* __restrict__ flags)
{
  int gid = blockIdx.x*256 + threadIdx.x;
  if (gid < 73728){
    int l = gid & 63, t2 = gid >> 6;
    int s = t2 % 9, tau = (t2/9) & 7, sl = (t2/72) & 7, d = t2/576;
    const float* Whh = d ? WhhB : WhhF;
    const float* Wih = d ? WihB : WihF;
    const float* bb  = d ? bB  : bF;
    int col = (tau>>1)*256 + sl*32 + 16*(tau&1) + (l&15);
    int kb = (l>>4)*8;
    unsigned short v[8];
    #pragma unroll
    for (int j=0;j<8;j++){
      int ko = kb + j;
      float val = 0.f;
      if (s < 8)            val = Whh[col*256 + s*32 + ko];
      else if (ko < 19)     val = Wih[col*19 + ko];
      else if (ko == 19)    val = bb[col];
      v[j] = f2bf(val);
    }
    u32x4 pk;
    pk[0] = (unsigned)v[0] | ((unsigned)v[1]<<16);
    pk[1] = (unsigned)v[2] | ((unsigned)v[3]<<16);
    pk[2] = (unsigned)v[4] | ((unsigned)v[5]<<16);
    pk[3] = (unsigned)v[6] | ((unsigned)v[7]<<16);
    *(u32x4*)&Wpk[(size_t)gid*8] = pk;
  } else if (gid < 75776){
    int g2 = gid - 73728;
    int l = g2 & 63, t2 = g2 >> 6;
    int s = t2 & 7, ty = (t2>>3) & 1, d = t2 >> 4;
    int col = ty*16 + (l&15);
    int kb = (l>>4)*8;
    unsigned short v[8];
    #pragma unroll
    for (int j=0;j<8;j++) v[j] = f2bf(outW[col*512 + d*256 + s*32 + kb + j]);
    u32x4 pk;
    pk[0] = (unsigned)v[0] | ((unsigned)v[1]<<16);
    pk[1] = (unsigned)v[2] | ((unsigned)v[3]<<16);
    pk[2] = (unsigned)v[4] | ((unsigned)v[5]<<16);
    pk[3] = (unsigned)v[6] | ((unsigned)v[7]<<16);
    *(u32x4*)&Wyk[(size_t)g2*8] = pk;
  } else if (gid < 75792){
    flags[gid - 75776] = 0;
  }
}

// ---------------------------------------------------------------------------
// Phase 1: 16 blocks = (dir 2) x (hidden slice 8), 512 threads (8 waves).
// Block (d, sblk): all 128 batches x 32 units (gate-major cols, 8 n-tiles).
// Wave w: mp=w>>1 -> m-tiles {2mp,2mp+1}; n0=w&1 -> gate tiles tau=2g+n0.
// B fully VGPR-resident (k-chunks 0..7; x-chunk streamed). A (h|x|1) in LDS,
// double buffered, 9 chunks x 8 m x 1KB. Chunk s<8 = slice s's h (exchanged
// cross-block via agent-scope atomics, parity-buffered), chunk 8 = x + 1.0.
// Lane cell update: acc tiles g=0..3 give i/f/g/o for unit uu=16*n0+cr,
// batches 16m+4q+i -> c,h in registers. y-projection by waves owning m=sblk.
// ---------------------------------------------------------------------------
__global__ __launch_bounds__(512, 2) void lstm_kernel(
    const float* loc, const float* tds, const int* dlen,
    const float* timeW, const float* timeB,
    const unsigned short* Wpk, const unsigned short* Wyk,
    unsigned short* y_ws, unsigned int* hg, int* flags)
{
  __shared__ unsigned short Albuf[2][36864];   // 2 x 73728 B
  __shared__ float tws[28];
  const int tid = threadIdx.x;
  const int w = tid >> 6, l = tid & 63;
  const int quad = l >> 4, cr = l & 15;
  const int mp = w >> 1, n0 = w & 1;
  const int m0 = 2*mp, m1 = 2*mp+1;
  const int bid = blockIdx.x, d = bid >> 3, sblk = bid & 7;

  { // zero both A buffers
    unsigned int* az = (unsigned int*)&Albuf[0][0];
    #pragma unroll 4
    for (int i = tid; i < 36864; i += 512) az[i] = 0u;
  }
  if (tid < 24) tws[tid] = timeW[tid];
  else if (tid < 27) tws[tid] = timeB[tid-24];
  __syncthreads();
  if (tid < 256){ // constant 1.0 at x-chunk ko=19 (bias lane), both buffers
    int pb = tid >> 7, m = (tid>>4)&7, r = tid & 15;
    Albuf[pb][(64 + m)*512 + (32 + r)*8 + 3] = 0x3F80;
  }

  const s16x8* BP = (const s16x8*)Wpk;
  const s16x8* YP = (const s16x8*)Wyk;
  const int bbase = ((d*8 + sblk)*8)*9*64;

  // resident gate weights: k-chunks 0..7
  s16x8 Bv[8][4];
  #pragma unroll
  for (int s=0;s<8;s++)
    #pragma unroll
    for (int g=0;g<4;g++)
      Bv[s][g] = BP[bbase + ((2*g + n0)*9 + s)*64 + l];

  int lens0[4], lens1[4];
  #pragma unroll
  for (int i=0;i<4;i++){
    lens0[i] = dlen[16*m0 + 4*quad + i];
    lens1[i] = dlen[16*m1 + 4*quad + i];
  }
  const int maxlen = dlen[0];

  float c0[4], h0[4], c1[4], h1[4];
  #pragma unroll
  for (int i=0;i<4;i++){ c0[i]=0.f; h0[i]=0.f; c1[i]=0.f; h1[i]=0.f; }

  const int mx = 2*mp + n0;   // this wave's x-staging m-tile
  auto stage_x = [&](int buf, int tn){
    { // loc dense: 16 dims
      int rb = l >> 2, dq = l & 3;
      const float* px = &loc[(((size_t)(16*mx + rb))*TT + tn)*16 + dq*4];
      f32x4 xa = *(const f32x4*)px;
      unsigned int u0 = (unsigned)f2bf(xa[0]) | ((unsigned)f2bf(xa[1])<<16);
      unsigned int u1 = (unsigned)f2bf(xa[2]) | ((unsigned)f2bf(xa[3])<<16);
      int k0 = dq*4;
      int off = (64+mx)*1024 + ((k0>>3)*16 + rb)*16 + (k0&7)*2;
      *(u32x2*)((char*)&Albuf[buf][0] + off) = (u32x2){u0,u1};
    }
    if (quad < 3){ // time embed dims 16..18
      const float* pt = &tds[(((size_t)(16*mx + cr))*TT + tn)*8];
      f32x4 t0 = *(const f32x4*)pt, t1 = *(const f32x4*)(pt+4);
      float td = tws[24+quad];
      #pragma unroll
      for (int dd=0; dd<4; dd++) td += t0[dd]*tws[quad*8+dd] + t1[dd]*tws[quad*8+4+dd];
      Albuf[buf][(64+mx)*512 + (32+cr)*8 + quad] = f2bf(td);
    }
  };

  __syncthreads();
  { int t0 = d ? (maxlen-1) : 0; stage_x(0, t0); }
  __syncthreads();

  int p = 0;
  for (int vs = 0; vs <= maxlen; vs++){
    bool do_g = (vs < maxlen);
    int tg = d ? (maxlen-1-vs) : vs;
    int ty = d ? (maxlen-vs)   : (vs-1);

    // ---- (a) publish flag, poll peers, stage remote h(vs-1) into A[p] ----
    if (vs >= 1){
      if (tid == 0)
        __hip_atomic_store(&flags[d*8+sblk], vs, __ATOMIC_RELEASE, __HIP_MEMORY_SCOPE_AGENT);
      for(;;){
        int v = vs;
        if (l < 8 && l != sblk)
          v = __hip_atomic_load(&flags[d*8+l], __ATOMIC_ACQUIRE, __HIP_MEMORY_SCOPE_AGENT);
        if (!__any(v < vs)) break;
        __builtin_amdgcn_s_sleep(1);
      }
      unsigned int* hgp = hg + (((size_t)((vs-1)&1)*2 + d)*8)*2048;
      unsigned int* lp = (unsigned int*)&Albuf[p][0];
      #pragma unroll
      for (int ri=0; ri<7; ri++){
        int r = ri + (ri >= sblk ? 1 : 0);
        #pragma unroll
        for (int jh=0; jh<2; jh++){
          int idx = r*2048 + jh*1024 + 2*tid;
          unsigned int u0 = __hip_atomic_load(hgp + idx,     __ATOMIC_RELAXED, __HIP_MEMORY_SCOPE_AGENT);
          unsigned int u1 = __hip_atomic_load(hgp + idx + 1, __ATOMIC_RELAXED, __HIP_MEMORY_SCOPE_AGENT);
          *(u32x2*)&lp[idx] = (u32x2){u0,u1};
        }
      }
    }
    __syncthreads();   // (b)

    const s16x8* ap = (const s16x8*)&Albuf[p][0];

    // ---- y projection of h(ty) (full h staged in A[p]); waves with m==sblk ----
    if (vs > 0 && mp == (sblk>>1)){
      f32x4 yacc = {0.f,0.f,0.f,0.f};
      #pragma unroll
      for (int s=0;s<8;s++){
        s16x8 ya = ap[(s*8 + sblk)*64 + l];
        s16x8 yb = YP[((d*2 + n0)*8 + s)*64 + l];
        yacc = __builtin_amdgcn_mfma_f32_16x16x32_bf16(ya, yb, yacc, 0,0,0);
      }
      size_t yb_ = ((size_t)(d*8 + sblk)*TT + (size_t)ty)*512;
      #pragma unroll
      for (int i=0;i<4;i++)
        y_ws[yb_ + (size_t)(4*quad+i)*32 + n0*16 + cr] = f2bf(yacc[i]);
    }

    // ---- gates + cell ----
    if (do_g){
      s16x8 bx[4];
      #pragma unroll
      for (int g=0;g<4;g++) bx[g] = BP[bbase + ((2*g+n0)*9 + 8)*64 + l];

      f32x4 acc0[4], acc1[4];
      s16x8 a0 = ap[(0*8+m0)*64 + l], a1 = ap[(0*8+m1)*64 + l];
      #pragma unroll
      for (int s=0;s<9;s++){
        s16x8 a0n, a1n;
        if (s < 8){ a0n = ap[((s+1)*8+m0)*64 + l]; a1n = ap[((s+1)*8+m1)*64 + l]; }
        #pragma unroll
        for (int g=0;g<4;g++){
          s16x8 bb = (s < 8) ? Bv[s][g] : bx[g];
          if (s == 0){
            f32x4 zz = {0.f,0.f,0.f,0.f};
            acc0[g] = __builtin_amdgcn_mfma_f32_16x16x32_bf16(a0, bb, zz, 0,0,0);
            acc1[g] = __builtin_amdgcn_mfma_f32_16x16x32_bf16(a1, bb, zz, 0,0,0);
          } else {
            acc0[g] = __builtin_amdgcn_mfma_f32_16x16x32_bf16(a0, bb, acc0[g], 0,0,0);
            acc1[g] = __builtin_amdgcn_mfma_f32_16x16x32_bf16(a1, bb, acc1[g], 0,0,0);
          }
        }
        a0 = a0n; a1 = a1n;
      }

      #pragma unroll
      for (int i=0;i<4;i++){
        { float cn = sigm(acc0[1][i])*c0[i] + sigm(acc0[0][i])*tanh_(acc0[2][i]);
          float hn = sigm(acc0[3][i])*tanh_(cn);
          bool mk = (tg < lens0[i]);
          c0[i] = mk ? cn : c0[i]; h0[i] = mk ? hn : h0[i]; }
        { float cn = sigm(acc1[1][i])*c1[i] + sigm(acc1[0][i])*tanh_(acc1[2][i]);
          float hn = sigm(acc1[3][i])*tanh_(cn);
          bool mk = (tg < lens1[i]);
          c1[i] = mk ? cn : c1[i]; h1[i] = mk ? hn : h1[i]; }
      }

      // write h(vs): LDS own chunk of A[p^1] + global publish (agent atomics)
      int wb = p ^ 1;
      int uu = 16*n0 + cr;
      unsigned int* hgw = hg + ((((size_t)(vs&1)*2 + d)*8 + sblk))*2048;
      unsigned int* lw = (unsigned int*)&Albuf[wb][0];
      bool evn = (cr & 1) == 0;
      int lpr = (uu>>3)*16 + 4*quad;
      int jd = (uu&7) >> 1;
      #pragma unroll
      for (int i=0;i<4;i++){
        float o0 = __shfl_xor(h0[i], 1, 64);
        float o1 = __shfl_xor(h1[i], 1, 64);
        if (evn){
          unsigned int v0 = (unsigned)f2bf(h0[i]) | ((unsigned)f2bf(o0)<<16);
          unsigned int v1 = (unsigned)f2bf(h1[i]) | ((unsigned)f2bf(o1)<<16);
          int dws = (lpr + i)*4 + jd;
          lw[(sblk*8 + m0)*256 + dws] = v0;
          lw[(sblk*8 + m1)*256 + dws] = v1;
          __hip_atomic_store(hgw + m0*256 + dws, v0, __ATOMIC_RELAXED, __HIP_MEMORY_SCOPE_AGENT);
          __hip_atomic_store(hgw + m1*256 + dws, v1, __ATOMIC_RELAXED, __HIP_MEMORY_SCOPE_AGENT);
        }
      }

      // stage x for next step into A[p^1]
      int tn = d ? (tg-1) : (tg+1);
      if (tn >= 0 && tn < TT) stage_x(wb, tn);
    }
    __syncthreads();   // (d)
    p ^= 1;
  }
}

// ---------------------------------------------------------------------------
// Phase 2: per-batch head: tanh(y_f+y_b+addr_feat) . comb_W, masked log_softmax.
// ---------------------------------------------------------------------------
__global__ __launch_bounds__(256) void combine_kernel(
    const unsigned short* __restrict__ y_ws,
    const float* __restrict__ addr, const int* __restrict__ addr_type,
    const float* __restrict__ poi, const float* __restrict__ addrW,
    const float* __restrict__ addrB, const float* __restrict__ combW,
    const int* __restrict__ dlen, float* __restrict__ out)
{
  int b = blockIdx.x, tid = threadIdx.x;
  int grp = b >> 4, row = b & 15;
  __shared__ float af[32], cw[32], red[256];
  if (tid < 32){
    float s = addrB[tid] + addrW[tid*4]*addr[b];
    int at = addr_type[b];
    #pragma unroll
    for (int e=0;e<3;e++) s += addrW[tid*4+1+e]*poi[at*3+e];
    af[tid] = s;
    cw[tid] = combW[tid];
  }
  __syncthreads();
  int len = dlen[b];
  float sv[4];
  float lmax = -3.0e38f;
  #pragma unroll
  for (int kk=0;kk<4;kk++){
    int t = tid + kk*256;
    const u32x4* pf = (const u32x4*)(y_ws + ((((size_t)grp)*TT + t)*16 + row)*32);
    const u32x4* pb = (const u32x4*)(y_ws + ((((size_t)(8+grp))*TT + t)*16 + row)*32);
    float s = 0.f;
    #pragma unroll
    for (int ck=0; ck<4; ck++){
      u32x4 uf = pf[ck], ub = pb[ck];
      #pragma unroll
      for (int e=0;e<4;e++){
        int j = ck*8 + e*2;
        float v0 = bflo(uf[e]) + bflo(ub[e]) + af[j];
        float v1 = bfhi(uf[e]) + bfhi(ub[e]) + af[j+1];
        s += cw[j]*tanh_(v0) + cw[j+1]*tanh_(v1);
      }
    }
    sv[kk] = s;
    if (t < len) lmax = fmaxf(lmax, s);
  }
  red[tid] = lmax; __syncthreads();
  for (int off=128; off>0; off>>=1){
    if (tid < off) red[tid] = fmaxf(red[tid], red[tid+off]);
    __syncthreads();
  }
  float gmax = red[0];
  __syncthreads();
  float ls = 0.f;
  #pragma unroll
  for (int kk=0;kk<4;kk++){
    int t = tid + kk*256;
    if (t < len) ls += ex2(LOG2E*(sv[kk]-gmax));
  }
  red[tid] = ls; __syncthreads();
  for (int off=128; off>0; off>>=1){
    if (tid < off) red[tid] += red[tid+off];
    __syncthreads();
  }
  float lnz = __builtin_amdgcn_logf(red[0]) * (1.f/LOG2E);
  #pragma unroll
  for (int kk=0;kk<4;kk++){
    int t = tid + kk*256;
    out[(size_t)b*TT + t] = (t < len) ? (sv[kk]-gmax-lnz) : 0.f;
  }
}

// ---------------------------------------------------------------------------
extern "C" void kernel_launch(void* const* d_in, const int* in_sizes, int n_in,
                              void* d_out, int out_size, void* d_ws, size_t ws_size,
                              hipStream_t stream)
{
  const float* addr  = (const float*)d_in[0];
  const int*   atyp  = (const int*)d_in[1];
  const float* loc   = (const float*)d_in[2];
  const float* tdsq  = (const float*)d_in[3];
  const int*   dlen  = (const int*)d_in[4];
  const float* poi   = (const float*)d_in[5];
  const float* timeW = (const float*)d_in[6];
  const float* timeB = (const float*)d_in[7];
  const float* addrW = (const float*)d_in[8];
  const float* addrB = (const float*)d_in[9];
  const float* WihF  = (const float*)d_in[10];
  const float* WhhF  = (const float*)d_in[11];
  const float* bF    = (const float*)d_in[12];
  const float* WihB  = (const float*)d_in[13];
  const float* WhhB  = (const float*)d_in[14];
  const float* bB    = (const float*)d_in[15];
  const float* outW  = (const float*)d_in[16];
  const float* combW = (const float*)d_in[17];

  // workspace layout (all inside d_ws; ~18.3 MB total):
  char* wsb = (char*)d_ws;
  unsigned short* Wpk   = (unsigned short*)wsb;               // 1,179,648 B
  unsigned short* y_ws  = (unsigned short*)(wsb + 1216512);   // 16,777,216 B
  int*            flags = (int*)(wsb + 17993728);             // 64 B (pad to 1 KB)
  unsigned short* Wyk   = (unsigned short*)(wsb + 17994752);  // 32,768 B
  unsigned int*   hg    = (unsigned int*)(wsb + 18027520);    // 262,144 B
  float* outp = (float*)d_out;

  pack_weights<<<297, 256, 0, stream>>>(WhhF, WihF, bF, WhhB, WihB, bB, outW, Wpk, Wyk, flags);
  lstm_kernel<<<16, 512, 0, stream>>>(loc, tdsq, dlen, timeW, timeB, Wpk, Wyk, y_ws, hg, flags);
  combine_kernel<<<128, 256, 0, stream>>>(y_ws, addr, atyp, poi, addrW, addrB, combW, dlen, outp);
}

// Round 5
// 9671.864 us; speedup vs baseline: 1.1981x; 1.1981x over previous
//
#include <hip/hip_runtime.h>

#define TT 1024
#define LOG2E 1.44269504088896340736f

typedef __attribute__((ext_vector_type(8))) short s16x8;
typedef __attribute__((ext_vector_type(4))) float f32x4;
typedef __attribute__((ext_vector_type(4))) unsigned int u32x4;
typedef __attribute__((ext_vector_type(2))) unsigned int u32x2;

__device__ __forceinline__ float ex2(float x){ return __builtin_amdgcn_exp2f(x); }
__device__ __forceinline__ float rcp_(float x){ return __builtin_amdgcn_rcpf(x); }
__device__ __forceinline__ float sigm(float x){ return rcp_(1.f + ex2(-LOG2E*x)); }
__device__ __forceinline__ float tanh_(float x){
  float t = ex2(2.f*LOG2E*x);
  return 1.f - 2.f*rcp_(t + 1.f);
}
__device__ __forceinline__ unsigned short f2bf(float f){
  unsigned int u = __float_as_uint(f);
  u += 0x7fffu + ((u>>16)&1u);
  return (unsigned short)(u>>16);
}
__device__ __forceinline__ float bflo(unsigned int u){ return __uint_as_float(u << 16); }
__device__ __forceinline__ float bfhi(unsigned int u){ return __uint_as_float(u & 0xffff0000u); }

// ---------------------------------------------------------------------------
// Phase 0: pack weights, B-fragment layout, bf16.
// Wpk gates: [d(2)][slice(8)][tau(8)][s(9)][lane(64)][8]
//   col = (tau>>1)*256 + slice*32 + 16*(tau&1) + (lane&15)   (gate g = tau>>1)
//   ko  = (lane>>4)*8 + j ; k-chunk s<8 -> Whh[col][s*32+ko];
//   s==8: ko<19 -> Wih[col][ko]; ko==19 -> bias[col]; else 0   (A has 1.0 at ko19)
// Wyk: [d][tauy(2)][s(8)][lane][8]: col = tauy*16+(lane&15); outW[col][d*256+s*32+ko]
// Also zeroes the 16 sync flags.
// ---------------------------------------------------------------------------
__global__ __launch_bounds__(256) void pack_weights(
    const float* __restrict__ WhhF, const float* __restrict__ WihF, const float* __restrict__ bF,
    const float* __restrict__ WhhB, const float* __restrict__ WihB, const float* __restrict__ bB,
    const float* __restrict__ outW,
    unsigned short* __restrict__ Wpk, unsigned short* __restrict__ Wyk, int* __restrict__ flags)
{
  int gid = blockIdx.x*256 + threadIdx.x;
  if (gid < 73728){
    int l = gid & 63, t2 = gid >> 6;
    int s = t2 % 9, tau = (t2/9) & 7, sl = (t2/72) & 7, d = t2/576;
    const float* Whh = d ? WhhB : WhhF;
    const float* Wih = d ? WihB : WihF;
    const float* bb  = d ? bB  : bF;
    int col = (tau>>1)*256 + sl*32 + 16*(tau&1) + (l&15);
    int kb = (l>>4)*8;
    unsigned short v[8];
    #pragma unroll
    for (int j=0;j<8;j++){
      int ko = kb + j;
      float val = 0.f;
      if (s < 8)            val = Whh[col*256 + s*32 + ko];
      else if (ko < 19)     val = Wih[col*19 + ko];
      else if (ko == 19)    val = bb[col];
      v[j] = f2bf(val);
    }
    u32x4 pk;
    pk[0] = (unsigned)v[0] | ((unsigned)v[1]<<16);
    pk[1] = (unsigned)v[2] | ((unsigned)v[3]<<16);
    pk[2] = (unsigned)v[4] | ((unsigned)v[5]<<16);
    pk[3] = (unsigned)v[6] | ((unsigned)v[7]<<16);
    *(u32x4*)&Wpk[(size_t)gid*8] = pk;
  } else if (gid < 75776){
    int g2 = gid - 73728;
    int l = g2 & 63, t2 = g2 >> 6;
    int s = t2 & 7, ty = (t2>>3) & 1, d = t2 >> 4;
    int col = ty*16 + (l&15);
    int kb = (l>>4)*8;
    unsigned short v[8];
    #pragma unroll
    for (int j=0;j<8;j++) v[j] = f2bf(outW[col*512 + d*256 + s*32 + kb + j]);
    u32x4 pk;
    pk[0] = (unsigned)v[0] | ((unsigned)v[1]<<16);
    pk[1] = (unsigned)v[2] | ((unsigned)v[3]<<16);
    pk[2] = (unsigned)v[4] | ((unsigned)v[5]<<16);
    pk[3] = (unsigned)v[6] | ((unsigned)v[7]<<16);
    *(u32x4*)&Wyk[(size_t)g2*8] = pk;
  } else if (gid < 75792){
    flags[gid - 75776] = 0;
  }
}

// ---------------------------------------------------------------------------
// Phase 1: 16 blocks = (dir 2) x (hidden slice 8), 512 threads (8 waves).
// Block (d, sblk): all 128 batches x 32 units (gate-major cols, 8 n-tiles).
// Wave w: mp=w>>1 -> m-tiles {2mp,2mp+1}; n0=w&1 -> gate tiles tau=2g+n0.
// B fully register-resident (k-chunks 0..7; x-chunk streamed). A (h|x|1) in
// LDS, double buffered. Chunk s<8 = slice s's h (exchanged cross-block via
// coherent sc0+sc1 loads, parity-buffered, flag handshake), chunk 8 = x + 1.0.
// Exchange reads batched as 7x global_load_dwordx4 sc0 sc1 + ONE waitcnt,
// with next-step x staging overlapped in flight (round-5 fix: the per-atomic
// waitcnt serialization cost ~19k cyc/step in round 4).
// ---------------------------------------------------------------------------
__global__ __launch_bounds__(512, 2) void lstm_kernel(
    const float* loc, const float* tds, const int* dlen,
    const float* timeW, const float* timeB,
    const unsigned short* Wpk, const unsigned short* Wyk,
    unsigned short* y_ws, unsigned int* hg, int* flags)
{
  __shared__ unsigned short Albuf[2][36864];   // 2 x 73728 B
  __shared__ float tws[28];
  const int tid = threadIdx.x;
  const int w = tid >> 6, l = tid & 63;
  const int quad = l >> 4, cr = l & 15;
  const int mp = w >> 1, n0 = w & 1;
  const int m0 = 2*mp, m1 = 2*mp+1;
  const int bid = blockIdx.x, d = bid >> 3, sblk = bid & 7;

  { // zero both A buffers
    unsigned int* az = (unsigned int*)&Albuf[0][0];
    #pragma unroll 4
    for (int i = tid; i < 36864; i += 512) az[i] = 0u;
  }
  if (tid < 24) tws[tid] = timeW[tid];
  else if (tid < 27) tws[tid] = timeB[tid-24];
  __syncthreads();
  if (tid < 256){ // constant 1.0 at x-chunk ko=19 (bias lane), both buffers
    int pb = tid >> 7, m = (tid>>4)&7, r = tid & 15;
    Albuf[pb][(64 + m)*512 + (32 + r)*8 + 3] = 0x3F80;
  }

  const s16x8* BP = (const s16x8*)Wpk;
  const s16x8* YP = (const s16x8*)Wyk;
  const int bbase = ((d*8 + sblk)*8)*9*64;

  // resident gate weights: k-chunks 0..7
  s16x8 Bv[8][4];
  #pragma unroll
  for (int s=0;s<8;s++)
    #pragma unroll
    for (int g=0;g<4;g++)
      Bv[s][g] = BP[bbase + ((2*g + n0)*9 + s)*64 + l];

  int lens0[4], lens1[4];
  #pragma unroll
  for (int i=0;i<4;i++){
    lens0[i] = dlen[16*m0 + 4*quad + i];
    lens1[i] = dlen[16*m1 + 4*quad + i];
  }
  const int maxlen = dlen[0];

  float c0[4], h0[4], c1[4], h1[4];
  #pragma unroll
  for (int i=0;i<4;i++){ c0[i]=0.f; h0[i]=0.f; c1[i]=0.f; h1[i]=0.f; }

  const int mx = 2*mp + n0;   // this wave's x-staging m-tile
  auto stage_x = [&](int buf, int tn){
    { // loc dense: 16 dims
      int rb = l >> 2, dq = l & 3;
      const float* px = &loc[(((size_t)(16*mx + rb))*TT + tn)*16 + dq*4];
      f32x4 xa = *(const f32x4*)px;
      unsigned int u0 = (unsigned)f2bf(xa[0]) | ((unsigned)f2bf(xa[1])<<16);
      unsigned int u1 = (unsigned)f2bf(xa[2]) | ((unsigned)f2bf(xa[3])<<16);
      int k0 = dq*4;
      int off = (64+mx)*1024 + ((k0>>3)*16 + rb)*16 + (k0&7)*2;
      *(u32x2*)((char*)&Albuf[buf][0] + off) = (u32x2){u0,u1};
    }
    if (quad < 3){ // time embed dims 16..18
      const float* pt = &tds[(((size_t)(16*mx + cr))*TT + tn)*8];
      f32x4 t0 = *(const f32x4*)pt, t1 = *(const f32x4*)(pt+4);
      float td = tws[24+quad];
      #pragma unroll
      for (int dd=0; dd<4; dd++) td += t0[dd]*tws[quad*8+dd] + t1[dd]*tws[quad*8+4+dd];
      Albuf[buf][(64+mx)*512 + (32+cr)*8 + quad] = f2bf(td);
    }
  };

  __syncthreads();
  { int t0 = d ? (maxlen-1) : 0; stage_x(0, t0); }
  __syncthreads();

  int p = 0;
  for (int vs = 0; vs <= maxlen; vs++){
    bool do_g = (vs < maxlen);
    int tg = d ? (maxlen-1-vs) : vs;
    int ty = d ? (maxlen-vs)   : (vs-1);

    // ---- (a) publish flag, poll peers, issue batched exchange loads ----
    u32x4 rv[7];
    if (vs >= 1){
      if (tid == 0)
        __hip_atomic_store(&flags[d*8+sblk], vs, __ATOMIC_RELEASE, __HIP_MEMORY_SCOPE_AGENT);
      for(;;){
        int v = vs;
        if (l < 8 && l != sblk)
          v = __hip_atomic_load(&flags[d*8+l], __ATOMIC_ACQUIRE, __HIP_MEMORY_SCOPE_AGENT);
        if (!__any(v < vs)) break;
        __builtin_amdgcn_s_sleep(1);
      }
      const unsigned int* hgp = hg + (((size_t)((vs-1)&1)*2 + d)*8)*2048;
      // issue all 7 coherent 16B loads back-to-back (no per-load waits)
      #pragma unroll
      for (int ri=0; ri<7; ri++){
        int r = ri + (ri >= sblk ? 1 : 0);
        const unsigned int* srcp = hgp + r*2048 + 4*tid;
        asm volatile("global_load_dwordx4 %0, %1, off sc0 sc1"
                     : "=v"(rv[ri]) : "v"(srcp) : "memory");
      }
    }

    // ---- stage next x into A[p^1] while exchange loads are in flight ----
    if (do_g){
      int tn = d ? (tg-1) : (tg+1);
      if (tn >= 0 && tn < TT) stage_x(p ^ 1, tn);
    }

    // ---- drain exchange loads, store to LDS ----
    if (vs >= 1){
      asm volatile("s_waitcnt vmcnt(0)" ::: "memory");
      unsigned int* lp = (unsigned int*)&Albuf[p][0];
      #pragma unroll
      for (int ri=0; ri<7; ri++){
        int r = ri + (ri >= sblk ? 1 : 0);
        *(u32x4*)&lp[r*2048 + 4*tid] = rv[ri];
      }
    }
    __syncthreads();   // (b)

    const s16x8* ap = (const s16x8*)&Albuf[p][0];

    // ---- y projection of h(ty) (full h staged in A[p]); waves with m==sblk ----
    if (vs > 0 && mp == (sblk>>1)){
      f32x4 yacc = {0.f,0.f,0.f,0.f};
      #pragma unroll
      for (int s=0;s<8;s++){
        s16x8 ya = ap[(s*8 + sblk)*64 + l];
        s16x8 yb = YP[((d*2 + n0)*8 + s)*64 + l];
        yacc = __builtin_amdgcn_mfma_f32_16x16x32_bf16(ya, yb, yacc, 0,0,0);
      }
      size_t yb_ = ((size_t)(d*8 + sblk)*TT + (size_t)ty)*512;
      #pragma unroll
      for (int i=0;i<4;i++)
        y_ws[yb_ + (size_t)(4*quad+i)*32 + n0*16 + cr] = f2bf(yacc[i]);
    }

    // ---- gates + cell ----
    if (do_g){
      s16x8 bx[4];
      #pragma unroll
      for (int g=0;g<4;g++) bx[g] = BP[bbase + ((2*g+n0)*9 + 8)*64 + l];

      f32x4 acc0[4], acc1[4];
      s16x8 a0 = ap[(0*8+m0)*64 + l], a1 = ap[(0*8+m1)*64 + l];
      #pragma unroll
      for (int s=0;s<9;s++){
        s16x8 a0n, a1n;
        if (s < 8){ a0n = ap[((s+1)*8+m0)*64 + l]; a1n = ap[((s+1)*8+m1)*64 + l]; }
        #pragma unroll
        for (int g=0;g<4;g++){
          s16x8 bb = (s < 8) ? Bv[s][g] : bx[g];
          if (s == 0){
            f32x4 zz = {0.f,0.f,0.f,0.f};
            acc0[g] = __builtin_amdgcn_mfma_f32_16x16x32_bf16(a0, bb, zz, 0,0,0);
            acc1[g] = __builtin_amdgcn_mfma_f32_16x16x32_bf16(a1, bb, zz, 0,0,0);
          } else {
            acc0[g] = __builtin_amdgcn_mfma_f32_16x16x32_bf16(a0, bb, acc0[g], 0,0,0);
            acc1[g] = __builtin_amdgcn_mfma_f32_16x16x32_bf16(a1, bb, acc1[g], 0,0,0);
          }
        }
        a0 = a0n; a1 = a1n;
      }

      #pragma unroll
      for (int i=0;i<4;i++){
        { float cn = sigm(acc0[1][i])*c0[i] + sigm(acc0[0][i])*tanh_(acc0[2][i]);
          float hn = sigm(acc0[3][i])*tanh_(cn);
          bool mk = (tg < lens0[i]);
          c0[i] = mk ? cn : c0[i]; h0[i] = mk ? hn : h0[i]; }
        { float cn = sigm(acc1[1][i])*c1[i] + sigm(acc1[0][i])*tanh_(acc1[2][i]);
          float hn = sigm(acc1[3][i])*tanh_(cn);
          bool mk = (tg < lens1[i]);
          c1[i] = mk ? cn : c1[i]; h1[i] = mk ? hn : h1[i]; }
      }

      // write h(vs): LDS own chunk of A[p^1] + global publish (agent atomics)
      int wb = p ^ 1;
      int uu = 16*n0 + cr;
      unsigned int* hgw = hg + ((((size_t)(vs&1)*2 + d)*8 + sblk))*2048;
      unsigned int* lw = (unsigned int*)&Albuf[wb][0];
      bool evn = (cr & 1) == 0;
      int lpr = (uu>>3)*16 + 4*quad;
      int jd = (uu&7) >> 1;
      #pragma unroll
      for (int i=0;i<4;i++){
        float o0 = __shfl_xor(h0[i], 1, 64);
        float o1 = __shfl_xor(h1[i], 1, 64);
        if (evn){
          unsigned int v0 = (unsigned)f2bf(h0[i]) | ((unsigned)f2bf(o0)<<16);
          unsigned int v1 = (unsigned)f2bf(h1[i]) | ((unsigned)f2bf(o1)<<16);
          int dws = (lpr + i)*4 + jd;
          lw[(sblk*8 + m0)*256 + dws] = v0;
          lw[(sblk*8 + m1)*256 + dws] = v1;
          __hip_atomic_store(hgw + m0*256 + dws, v0, __ATOMIC_RELAXED, __HIP_MEMORY_SCOPE_AGENT);
          __hip_atomic_store(hgw + m1*256 + dws, v1, __ATOMIC_RELAXED, __HIP_MEMORY_SCOPE_AGENT);
        }
      }
    }
    __syncthreads();   // (d)
    p ^= 1;
  }
}

// ---------------------------------------------------------------------------
// Phase 2: per-batch head: tanh(y_f+y_b+addr_feat) . comb_W, masked log_softmax.
// ---------------------------------------------------------------------------
__global__ __launch_bounds__(256) void combine_kernel(
    const unsigned short* __restrict__ y_ws,
    const float* __restrict__ addr, const int* __restrict__ addr_type,
    const float* __restrict__ poi, const float* __restrict__ addrW,
    const float* __restrict__ addrB, const float* __restrict__ combW,
    const int* __restrict__ dlen, float* __restrict__ out)
{
  int b = blockIdx.x, tid = threadIdx.x;
  int grp = b >> 4, row = b & 15;
  __shared__ float af[32], cw[32], red[256];
  if (tid < 32){
    float s = addrB[tid] + addrW[tid*4]*addr[b];
    int at = addr_type[b];
    #pragma unroll
    for (int e=0;e<3;e++) s += addrW[tid*4+1+e]*poi[at*3+e];
    af[tid] = s;
    cw[tid] = combW[tid];
  }
  __syncthreads();
  int len = dlen[b];
  float sv[4];
  float lmax = -3.0e38f;
  #pragma unroll
  for (int kk=0;kk<4;kk++){
    int t = tid + kk*256;
    const u32x4* pf = (const u32x4*)(y_ws + ((((size_t)grp)*TT + t)*16 + row)*32);
    const u32x4* pb = (const u32x4*)(y_ws + ((((size_t)(8+grp))*TT + t)*16 + row)*32);
    float s = 0.f;
    #pragma unroll
    for (int ck=0; ck<4; ck++){
      u32x4 uf = pf[ck], ub = pb[ck];
      #pragma unroll
      for (int e=0;e<4;e++){
        int j = ck*8 + e*2;
        float v0 = bflo(uf[e]) + bflo(ub[e]) + af[j];
        float v1 = bfhi(uf[e]) + bfhi(ub[e]) + af[j+1];
        s += cw[j]*tanh_(v0) + cw[j+1]*tanh_(v1);
      }
    }
    sv[kk] = s;
    if (t < len) lmax = fmaxf(lmax, s);
  }
  red[tid] = lmax; __syncthreads();
  for (int off=128; off>0; off>>=1){
    if (tid < off) red[tid] = fmaxf(red[tid], red[tid+off]);
    __syncthreads();
  }
  float gmax = red[0];
  __syncthreads();
  float ls = 0.f;
  #pragma unroll
  for (int kk=0;kk<4;kk++){
    int t = tid + kk*256;
    if (t < len) ls += ex2(LOG2E*(sv[kk]-gmax));
  }
  red[tid] = ls; __syncthreads();
  for (int off=128; off>0; off>>=1){
    if (tid < off) red[tid] += red[tid+off];
    __syncthreads();
  }
  float lnz = __builtin_amdgcn_logf(red[0]) * (1.f/LOG2E);
  #pragma unroll
  for (int kk=0;kk<4;kk++){
    int t = tid + kk*256;
    out[(size_t)b*TT + t] = (t < len) ? (sv[kk]-gmax-lnz) : 0.f;
  }
}

// ---------------------------------------------------------------------------
extern "C" void kernel_launch(void* const* d_in, const int* in_sizes, int n_in,
                              void* d_out, int out_size, void* d_ws, size_t ws_size,
                              hipStream_t stream)
{
  const float* addr  = (const float*)d_in[0];
  const int*   atyp  = (const int*)d_in[1];
  const float* loc   = (const float*)d_in[2];
  const float* tdsq  = (const float*)d_in[3];
  const int*   dlen  = (const int*)d_in[4];
  const float* poi   = (const float*)d_in[5];
  const float* timeW = (const float*)d_in[6];
  const float* timeB = (const float*)d_in[7];
  const float* addrW = (const float*)d_in[8];
  const float* addrB = (const float*)d_in[9];
  const float* WihF  = (const float*)d_in[10];
  const float* WhhF  = (const float*)d_in[11];
  const float* bF    = (const float*)d_in[12];
  const float* WihB  = (const float*)d_in[13];
  const float* WhhB  = (const float*)d_in[14];
  const float* bB    = (const float*)d_in[15];
  const float* outW  = (const float*)d_in[16];
  const float* combW = (const float*)d_in[17];

  // workspace layout (all inside d_ws; ~18.3 MB total):
  char* wsb = (char*)d_ws;
  unsigned short* Wpk   = (unsigned short*)wsb;               // 1,179,648 B
  unsigned short* y_ws  = (unsigned short*)(wsb + 1216512);   // 16,777,216 B
  int*            flags = (int*)(wsb + 17993728);             // 64 B (pad to 1 KB)
  unsigned short* Wyk   = (unsigned short*)(wsb + 17994752);  // 32,768 B
  unsigned int*   hg    = (unsigned int*)(wsb + 18027520);    // 262,144 B
  float* outp = (float*)d_out;

  pack_weights<<<297, 256, 0, stream>>>(WhhF, WihF, bF, WhhB, WihB, bB, outW, Wpk, Wyk, flags);
  lstm_kernel<<<16, 512, 0, stream>>>(loc, tdsq, dlen, timeW, timeB, Wpk, Wyk, y_ws, hg, flags);
  combine_kernel<<<128, 256, 0, stream>>>(y_ws, addr, atyp, poi, addrW, addrB, combW, dlen, outp);
}

// Round 6
// 7773.730 us; speedup vs baseline: 1.4907x; 1.2442x over previous
//
#include <hip/hip_runtime.h>

#define TT 1024
#define LOG2E 1.44269504088896340736f

typedef __attribute__((ext_vector_type(8))) short s16x8;
typedef __attribute__((ext_vector_type(4))) float f32x4;
typedef __attribute__((ext_vector_type(4))) unsigned int u32x4;
typedef __attribute__((ext_vector_type(2))) unsigned int u32x2;

__device__ __forceinline__ float ex2(float x){ return __builtin_amdgcn_exp2f(x); }
__device__ __forceinline__ float rcp_(float x){ return __builtin_amdgcn_rcpf(x); }
__device__ __forceinline__ float sigm(float x){ return rcp_(1.f + ex2(-LOG2E*x)); }
__device__ __forceinline__ float tanh_(float x){
  float t = ex2(2.f*LOG2E*x);
  return 1.f - 2.f*rcp_(t + 1.f);
}
__device__ __forceinline__ unsigned short f2bf(float f){
  unsigned int u = __float_as_uint(f);
  u += 0x7fffu + ((u>>16)&1u);
  return (unsigned short)(u>>16);
}
__device__ __forceinline__ float bflo(unsigned int u){ return __uint_as_float(u << 16); }
__device__ __forceinline__ float bfhi(unsigned int u){ return __uint_as_float(u & 0xffff0000u); }

// ---------------------------------------------------------------------------
// Phase 0: pack weights, B-fragment layout, bf16.
// Wpk gates: [d(2)][slice(8)][tau(8)][s(9)][lane(64)][8]
//   col = (tau>>1)*256 + slice*32 + 16*(tau&1) + (lane&15)   (gate g = tau>>1)
//   ko  = (lane>>4)*8 + j ; k-chunk s<8 -> Whh[col][s*32+ko];
//   s==8: ko<19 -> Wih[col][ko]; ko==19 -> bias[col]; else 0   (A has 1.0 at ko19)
// Wyk: [d][tauy(2)][s(8)][lane][8]: col = tauy*16+(lane&15); outW[col][d*256+s*32+ko]
// Also zeroes the sync flags (16 slots x 32 ints = 128B apart each).
// ---------------------------------------------------------------------------
__global__ __launch_bounds__(256) void pack_weights(
    const float* __restrict__ WhhF, const float* __restrict__ WihF, const float* __restrict__ bF,
    const float* __restrict__ WhhB, const float* __restrict__ WihB, const float* __restrict__ bB,
    const float* __restrict__ outW,
    unsigned short* __restrict__ Wpk, unsigned short* __restrict__ Wyk, int* __restrict__ flags)
{
  int gid = blockIdx.x*256 + threadIdx.x;
  if (gid < 73728){
    int l = gid & 63, t2 = gid >> 6;
    int s = t2 % 9, tau = (t2/9) & 7, sl = (t2/72) & 7, d = t2/576;
    const float* Whh = d ? WhhB : WhhF;
    const float* Wih = d ? WihB : WihF;
    const float* bb  = d ? bB  : bF;
    int col = (tau>>1)*256 + sl*32 + 16*(tau&1) + (l&15);
    int kb = (l>>4)*8;
    unsigned short v[8];
    #pragma unroll
    for (int j=0;j<8;j++){
      int ko = kb + j;
      float val = 0.f;
      if (s < 8)            val = Whh[col*256 + s*32 + ko];
      else if (ko < 19)     val = Wih[col*19 + ko];
      else if (ko == 19)    val = bb[col];
      v[j] = f2bf(val);
    }
    u32x4 pk;
    pk[0] = (unsigned)v[0] | ((unsigned)v[1]<<16);
    pk[1] = (unsigned)v[2] | ((unsigned)v[3]<<16);
    pk[2] = (unsigned)v[4] | ((unsigned)v[5]<<16);
    pk[3] = (unsigned)v[6] | ((unsigned)v[7]<<16);
    *(u32x4*)&Wpk[(size_t)gid*8] = pk;
  } else if (gid < 75776){
    int g2 = gid - 73728;
    int l = g2 & 63, t2 = g2 >> 6;
    int s = t2 & 7, ty = (t2>>3) & 1, d = t2 >> 4;
    int col = ty*16 + (l&15);
    int kb = (l>>4)*8;
    unsigned short v[8];
    #pragma unroll
    for (int j=0;j<8;j++) v[j] = f2bf(outW[col*512 + d*256 + s*32 + kb + j]);
    u32x4 pk;
    pk[0] = (unsigned)v[0] | ((unsigned)v[1]<<16);
    pk[1] = (unsigned)v[2] | ((unsigned)v[3]<<16);
    pk[2] = (unsigned)v[4] | ((unsigned)v[5]<<16);
    pk[3] = (unsigned)v[6] | ((unsigned)v[7]<<16);
    *(u32x4*)&Wyk[(size_t)g2*8] = pk;
  } else if (gid < 76288){
    flags[gid - 75776] = 0;
  }
}

// ---------------------------------------------------------------------------
// Phase 1: 16 blocks = (dir 2) x (hidden slice 8), 512 threads (8 waves).
// Block (d, sblk): all 128 batches x 32 units (gate-major cols, 8 n-tiles).
// Wave w: mp=w>>1 -> m-tiles {2mp,2mp+1}; n0=w&1 -> gate tiles tau=2g+n0.
// B fully register-resident. A (h|x|1) in LDS, double buffered; h slices
// exchanged cross-block via coherent sc0+sc1 loads, parity-buffered.
// Round-6 fix: flag handshake was 128 waves spinning acquire-loads on ONE
// cache line (contention ~15k cyc/step). Now: flags 128B apart, only wave 0
// polls (relaxed), others held at a barrier.
// ---------------------------------------------------------------------------
__global__ __launch_bounds__(512, 2) void lstm_kernel(
    const float* loc, const float* tds, const int* dlen,
    const float* timeW, const float* timeB,
    const unsigned short* Wpk, const unsigned short* Wyk,
    unsigned short* y_ws, unsigned int* hg, int* flags)
{
  __shared__ unsigned short Albuf[2][36864];   // 2 x 73728 B
  __shared__ float tws[28];
  const int tid = threadIdx.x;
  const int w = tid >> 6, l = tid & 63;
  const int quad = l >> 4, cr = l & 15;
  const int mp = w >> 1, n0 = w & 1;
  const int m0 = 2*mp, m1 = 2*mp+1;
  const int bid = blockIdx.x, d = bid >> 3, sblk = bid & 7;

  { // zero both A buffers
    unsigned int* az = (unsigned int*)&Albuf[0][0];
    #pragma unroll 4
    for (int i = tid; i < 36864; i += 512) az[i] = 0u;
  }
  if (tid < 24) tws[tid] = timeW[tid];
  else if (tid < 27) tws[tid] = timeB[tid-24];
  __syncthreads();
  if (tid < 256){ // constant 1.0 at x-chunk ko=19 (bias lane), both buffers
    int pb = tid >> 7, m = (tid>>4)&7, r = tid & 15;
    Albuf[pb][(64 + m)*512 + (32 + r)*8 + 3] = 0x3F80;
  }

  const s16x8* BP = (const s16x8*)Wpk;
  const s16x8* YP = (const s16x8*)Wyk;
  const int bbase = ((d*8 + sblk)*8)*9*64;

  // resident gate weights: k-chunks 0..7
  s16x8 Bv[8][4];
  #pragma unroll
  for (int s=0;s<8;s++)
    #pragma unroll
    for (int g=0;g<4;g++)
      Bv[s][g] = BP[bbase + ((2*g + n0)*9 + s)*64 + l];

  int lens0[4], lens1[4];
  #pragma unroll
  for (int i=0;i<4;i++){
    lens0[i] = dlen[16*m0 + 4*quad + i];
    lens1[i] = dlen[16*m1 + 4*quad + i];
  }
  const int maxlen = dlen[0];

  float c0[4], h0[4], c1[4], h1[4];
  #pragma unroll
  for (int i=0;i<4;i++){ c0[i]=0.f; h0[i]=0.f; c1[i]=0.f; h1[i]=0.f; }

  const int mx = 2*mp + n0;   // this wave's x-staging m-tile
  auto stage_x = [&](int buf, int tn){
    { // loc dense: 16 dims
      int rb = l >> 2, dq = l & 3;
      const float* px = &loc[(((size_t)(16*mx + rb))*TT + tn)*16 + dq*4];
      f32x4 xa = *(const f32x4*)px;
      unsigned int u0 = (unsigned)f2bf(xa[0]) | ((unsigned)f2bf(xa[1])<<16);
      unsigned int u1 = (unsigned)f2bf(xa[2]) | ((unsigned)f2bf(xa[3])<<16);
      int k0 = dq*4;
      int off = (64+mx)*1024 + ((k0>>3)*16 + rb)*16 + (k0&7)*2;
      *(u32x2*)((char*)&Albuf[buf][0] + off) = (u32x2){u0,u1};
    }
    if (quad < 3){ // time embed dims 16..18
      const float* pt = &tds[(((size_t)(16*mx + cr))*TT + tn)*8];
      f32x4 t0 = *(const f32x4*)pt, t1 = *(const f32x4*)(pt+4);
      float td = tws[24+quad];
      #pragma unroll
      for (int dd=0; dd<4; dd++) td += t0[dd]*tws[quad*8+dd] + t1[dd]*tws[quad*8+4+dd];
      Albuf[buf][(64+mx)*512 + (32+cr)*8 + quad] = f2bf(td);
    }
  };

  __syncthreads();
  { int t0 = d ? (maxlen-1) : 0; stage_x(0, t0); }
  __syncthreads();

  int p = 0;
  for (int vs = 0; vs <= maxlen; vs++){
    bool do_g = (vs < maxlen);
    int tg = d ? (maxlen-1-vs) : vs;
    int ty = d ? (maxlen-vs)   : (vs-1);

    // ---- (a) wave 0 publishes flag + polls peers; others wait at barrier ----
    u32x4 rv[7];
    if (vs >= 1){
      if (w == 0){
        if (l == 0)
          __hip_atomic_store(&flags[(d*8+sblk)*32], vs, __ATOMIC_RELEASE, __HIP_MEMORY_SCOPE_AGENT);
        for(;;){
          int v = vs;
          if (l < 8 && l != sblk)
            v = __hip_atomic_load(&flags[(d*8+l)*32], __ATOMIC_RELAXED, __HIP_MEMORY_SCOPE_AGENT);
          if (!__any(v < vs)) break;
          __builtin_amdgcn_s_sleep(2);
        }
      }
      __syncthreads();   // release all waves once peers confirmed
      const unsigned int* hgp = hg + (((size_t)((vs-1)&1)*2 + d)*8)*2048;
      // issue all 7 coherent 16B loads back-to-back (no per-load waits)
      #pragma unroll
      for (int ri=0; ri<7; ri++){
        int r = ri + (ri >= sblk ? 1 : 0);
        const unsigned int* srcp = hgp + r*2048 + 4*tid;
        asm volatile("global_load_dwordx4 %0, %1, off sc0 sc1"
                     : "=v"(rv[ri]) : "v"(srcp) : "memory");
      }
    }

    // ---- stage next x into A[p^1] while exchange loads are in flight ----
    if (do_g){
      int tn = d ? (tg-1) : (tg+1);
      if (tn >= 0 && tn < TT) stage_x(p ^ 1, tn);
    }

    // ---- drain exchange loads, store to LDS ----
    if (vs >= 1){
      asm volatile("s_waitcnt vmcnt(0)" ::: "memory");
      unsigned int* lp = (unsigned int*)&Albuf[p][0];
      #pragma unroll
      for (int ri=0; ri<7; ri++){
        int r = ri + (ri >= sblk ? 1 : 0);
        *(u32x4*)&lp[r*2048 + 4*tid] = rv[ri];
      }
    }
    __syncthreads();   // (b)

    const s16x8* ap = (const s16x8*)&Albuf[p][0];

    // ---- y projection of h(ty) (full h staged in A[p]); waves with m==sblk ----
    if (vs > 0 && mp == (sblk>>1)){
      f32x4 yacc = {0.f,0.f,0.f,0.f};
      #pragma unroll
      for (int s=0;s<8;s++){
        s16x8 ya = ap[(s*8 + sblk)*64 + l];
        s16x8 yb = YP[((d*2 + n0)*8 + s)*64 + l];
        yacc = __builtin_amdgcn_mfma_f32_16x16x32_bf16(ya, yb, yacc, 0,0,0);
      }
      size_t yb_ = ((size_t)(d*8 + sblk)*TT + (size_t)ty)*512;
      #pragma unroll
      for (int i=0;i<4;i++)
        y_ws[yb_ + (size_t)(4*quad+i)*32 + n0*16 + cr] = f2bf(yacc[i]);
    }

    // ---- gates + cell ----
    if (do_g){
      s16x8 bx[4];
      #pragma unroll
      for (int g=0;g<4;g++) bx[g] = BP[bbase + ((2*g+n0)*9 + 8)*64 + l];

      f32x4 acc0[4], acc1[4];
      s16x8 a0 = ap[(0*8+m0)*64 + l], a1 = ap[(0*8+m1)*64 + l];
      #pragma unroll
      for (int s=0;s<9;s++){
        s16x8 a0n, a1n;
        if (s < 8){ a0n = ap[((s+1)*8+m0)*64 + l]; a1n = ap[((s+1)*8+m1)*64 + l]; }
        #pragma unroll
        for (int g=0;g<4;g++){
          s16x8 bb = (s < 8) ? Bv[s][g] : bx[g];
          if (s == 0){
            f32x4 zz = {0.f,0.f,0.f,0.f};
            acc0[g] = __builtin_amdgcn_mfma_f32_16x16x32_bf16(a0, bb, zz, 0,0,0);
            acc1[g] = __builtin_amdgcn_mfma_f32_16x16x32_bf16(a1, bb, zz, 0,0,0);
          } else {
            acc0[g] = __builtin_amdgcn_mfma_f32_16x16x32_bf16(a0, bb, acc0[g], 0,0,0);
            acc1[g] = __builtin_amdgcn_mfma_f32_16x16x32_bf16(a1, bb, acc1[g], 0,0,0);
          }
        }
        a0 = a0n; a1 = a1n;
      }

      #pragma unroll
      for (int i=0;i<4;i++){
        { float cn = sigm(acc0[1][i])*c0[i] + sigm(acc0[0][i])*tanh_(acc0[2][i]);
          float hn = sigm(acc0[3][i])*tanh_(cn);
          bool mk = (tg < lens0[i]);
          c0[i] = mk ? cn : c0[i]; h0[i] = mk ? hn : h0[i]; }
        { float cn = sigm(acc1[1][i])*c1[i] + sigm(acc1[0][i])*tanh_(acc1[2][i]);
          float hn = sigm(acc1[3][i])*tanh_(cn);
          bool mk = (tg < lens1[i]);
          c1[i] = mk ? cn : c1[i]; h1[i] = mk ? hn : h1[i]; }
      }

      // write h(vs): LDS own chunk of A[p^1] + global publish (agent atomics)
      int wb = p ^ 1;
      int uu = 16*n0 + cr;
      unsigned int* hgw = hg + ((((size_t)(vs&1)*2 + d)*8 + sblk))*2048;
      unsigned int* lw = (unsigned int*)&Albuf[wb][0];
      bool evn = (cr & 1) == 0;
      int lpr = (uu>>3)*16 + 4*quad;
      int jd = (uu&7) >> 1;
      #pragma unroll
      for (int i=0;i<4;i++){
        float o0 = __shfl_xor(h0[i], 1, 64);
        float o1 = __shfl_xor(h1[i], 1, 64);
        if (evn){
          unsigned int v0 = (unsigned)f2bf(h0[i]) | ((unsigned)f2bf(o0)<<16);
          unsigned int v1 = (unsigned)f2bf(h1[i]) | ((unsigned)f2bf(o1)<<16);
          int dws = (lpr + i)*4 + jd;
          lw[(sblk*8 + m0)*256 + dws] = v0;
          lw[(sblk*8 + m1)*256 + dws] = v1;
          __hip_atomic_store(hgw + m0*256 + dws, v0, __ATOMIC_RELAXED, __HIP_MEMORY_SCOPE_AGENT);
          __hip_atomic_store(hgw + m1*256 + dws, v1, __ATOMIC_RELAXED, __HIP_MEMORY_SCOPE_AGENT);
        }
      }
    }
    __syncthreads();   // (d) — drains h stores before next-iter flag publish
    p ^= 1;
  }
}

// ---------------------------------------------------------------------------
// Phase 2: per-batch head: tanh(y_f+y_b+addr_feat) . comb_W, masked log_softmax.
// ---------------------------------------------------------------------------
__global__ __launch_bounds__(256) void combine_kernel(
    const unsigned short* __restrict__ y_ws,
    const float* __restrict__ addr, const int* __restrict__ addr_type,
    const float* __restrict__ poi, const float* __restrict__ addrW,
    const float* __restrict__ addrB, const float* __restrict__ combW,
    const int* __restrict__ dlen, float* __restrict__ out)
{
  int b = blockIdx.x, tid = threadIdx.x;
  int grp = b >> 4, row = b & 15;
  __shared__ float af[32], cw[32], red[256];
  if (tid < 32){
    float s = addrB[tid] + addrW[tid*4]*addr[b];
    int at = addr_type[b];
    #pragma unroll
    for (int e=0;e<3;e++) s += addrW[tid*4+1+e]*poi[at*3+e];
    af[tid] = s;
    cw[tid] = combW[tid];
  }
  __syncthreads();
  int len = dlen[b];
  float sv[4];
  float lmax = -3.0e38f;
  #pragma unroll
  for (int kk=0;kk<4;kk++){
    int t = tid + kk*256;
    const u32x4* pf = (const u32x4*)(y_ws + ((((size_t)grp)*TT + t)*16 + row)*32);
    const u32x4* pb = (const u32x4*)(y_ws + ((((size_t)(8+grp))*TT + t)*16 + row)*32);
    float s = 0.f;
    #pragma unroll
    for (int ck=0; ck<4; ck++){
      u32x4 uf = pf[ck], ub = pb[ck];
      #pragma unroll
      for (int e=0;e<4;e++){
        int j = ck*8 + e*2;
        float v0 = bflo(uf[e]) + bflo(ub[e]) + af[j];
        float v1 = bfhi(uf[e]) + bfhi(ub[e]) + af[j+1];
        s += cw[j]*tanh_(v0) + cw[j+1]*tanh_(v1);
      }
    }
    sv[kk] = s;
    if (t < len) lmax = fmaxf(lmax, s);
  }
  red[tid] = lmax; __syncthreads();
  for (int off=128; off>0; off>>=1){
    if (tid < off) red[tid] = fmaxf(red[tid], red[tid+off]);
    __syncthreads();
  }
  float gmax = red[0];
  __syncthreads();
  float ls = 0.f;
  #pragma unroll
  for (int kk=0;kk<4;kk++){
    int t = tid + kk*256;
    if (t < len) ls += ex2(LOG2E*(sv[kk]-gmax));
  }
  red[tid] = ls; __syncthreads();
  for (int off=128; off>0; off>>=1){
    if (tid < off) red[tid] += red[tid+off];
    __syncthreads();
  }
  float lnz = __builtin_amdgcn_logf(red[0]) * (1.f/LOG2E);
  #pragma unroll
  for (int kk=0;kk<4;kk++){
    int t = tid + kk*256;
    out[(size_t)b*TT + t] = (t < len) ? (sv[kk]-gmax-lnz) : 0.f;
  }
}

// ---------------------------------------------------------------------------
extern "C" void kernel_launch(void* const* d_in, const int* in_sizes, int n_in,
                              void* d_out, int out_size, void* d_ws, size_t ws_size,
                              hipStream_t stream)
{
  const float* addr  = (const float*)d_in[0];
  const int*   atyp  = (const int*)d_in[1];
  const float* loc   = (const float*)d_in[2];
  const float* tdsq  = (const float*)d_in[3];
  const int*   dlen  = (const int*)d_in[4];
  const float* poi   = (const float*)d_in[5];
  const float* timeW = (const float*)d_in[6];
  const float* timeB = (const float*)d_in[7];
  const float* addrW = (const float*)d_in[8];
  const float* addrB = (const float*)d_in[9];
  const float* WihF  = (const float*)d_in[10];
  const float* WhhF  = (const float*)d_in[11];
  const float* bF    = (const float*)d_in[12];
  const float* WihB  = (const float*)d_in[13];
  const float* WhhB  = (const float*)d_in[14];
  const float* bB    = (const float*)d_in[15];
  const float* outW  = (const float*)d_in[16];
  const float* combW = (const float*)d_in[17];

  // workspace layout (all inside d_ws; ~18.3 MB total):
  char* wsb = (char*)d_ws;
  unsigned short* Wpk   = (unsigned short*)wsb;               // 1,179,648 B
  unsigned short* y_ws  = (unsigned short*)(wsb + 1216512);   // 16,777,216 B
  int*            flags = (int*)(wsb + 17993728);             // 2,048 B (16 x 128B)
  unsigned short* Wyk   = (unsigned short*)(wsb + 17995776);  // 32,768 B
  unsigned int*   hg    = (unsigned int*)(wsb + 18028544);    // 262,144 B
  float* outp = (float*)d_out;

  pack_weights<<<298, 256, 0, stream>>>(WhhF, WihF, bF, WhhB, WihB, bB, outW, Wpk, Wyk, flags);
  lstm_kernel<<<16, 512, 0, stream>>>(loc, tdsq, dlen, timeW, timeB, Wpk, Wyk, y_ws, hg, flags);
  combine_kernel<<<128, 256, 0, stream>>>(y_ws, addr, atyp, poi, addrW, addrB, combW, dlen, outp);
}